// Round 12
// baseline (24.123 us; speedup 1.0000x reference)
//
#include <hip/hip_runtime.h>
#include <math.h>

#define CANON_EPS 1e-4f
#define MAX_STAGE 1536  // atoms; block range above this falls back to global

// ---------------------------------------------------------------------------
// Branch-free 3x3 symmetric Jacobi eigensolver in f32, 4 cyclic sweeps.
// Columns of Q = eigenvectors; eigenvalues sorted ascending (matches eigh).
// ---------------------------------------------------------------------------
__device__ __forceinline__ void jacobi3_f32(float a00, float a11, float a22,
                                            float a01, float a02, float a12,
                                            float Q[3][3]) {
  float A00 = a00, A11 = a11, A22 = a22;
  float A01 = a01, A02 = a02, A12 = a12;
  float Q00 = 1.f, Q01 = 0.f, Q02 = 0.f;
  float Q10 = 0.f, Q11 = 1.f, Q12 = 0.f;
  float Q20 = 0.f, Q21 = 0.f, Q22 = 1.f;

#define ROT(App, Aqq, Apq, Akp, Akq, Qrp0, Qrq0, Qrp1, Qrq1, Qrp2, Qrq2)     \
  {                                                                          \
    float apq = Apq;                                                         \
    float theta = (Aqq - App) / (2.0f * apq);                                \
    float t = copysignf(1.0f, theta) /                                       \
              (fabsf(theta) + sqrtf(1.0f + theta * theta));                  \
    t = (apq == 0.0f) ? 0.0f : t; /* kills 0/0 NaN path */                   \
    float c = 1.0f / sqrtf(1.0f + t * t);                                    \
    float s = t * c;                                                         \
    App = App - t * apq;                                                     \
    Aqq = Aqq + t * apq;                                                     \
    Apq = 0.0f;                                                              \
    float akp = Akp, akq = Akq;                                              \
    Akp = c * akp - s * akq;                                                 \
    Akq = s * akp + c * akq;                                                 \
    float r0p = Qrp0, r0q = Qrq0;                                            \
    Qrp0 = c * r0p - s * r0q;                                                \
    Qrq0 = s * r0p + c * r0q;                                                \
    float r1p = Qrp1, r1q = Qrq1;                                            \
    Qrp1 = c * r1p - s * r1q;                                                \
    Qrq1 = s * r1p + c * r1q;                                                \
    float r2p = Qrp2, r2q = Qrq2;                                            \
    Qrp2 = c * r2p - s * r2q;                                                \
    Qrq2 = s * r2p + c * r2q;                                                \
  }

#pragma unroll
  for (int sweep = 0; sweep < 4; ++sweep) {
    ROT(A00, A11, A01, A02, A12, Q00, Q01, Q10, Q11, Q20, Q21);
    ROT(A00, A22, A02, A01, A12, Q00, Q02, Q10, Q12, Q20, Q22);
    ROT(A11, A22, A12, A01, A02, Q01, Q02, Q11, Q12, Q21, Q22);
  }
#undef ROT

  float w0 = A00, w1 = A11, w2 = A22;
#define CSWAP(wa, wb, qa0, qb0, qa1, qb1, qa2, qb2)                          \
  {                                                                          \
    bool sw = (wb) < (wa);                                                   \
    float tw = wa; wa = sw ? wb : wa; wb = sw ? tw : wb;                     \
    float t0 = qa0; qa0 = sw ? qb0 : qa0; qb0 = sw ? t0 : qb0;               \
    float t1 = qa1; qa1 = sw ? qb1 : qa1; qb1 = sw ? t1 : qb1;               \
    float t2 = qa2; qa2 = sw ? qb2 : qa2; qb2 = sw ? t2 : qb2;               \
  }
  CSWAP(w0, w1, Q00, Q01, Q10, Q11, Q20, Q21);
  CSWAP(w1, w2, Q01, Q02, Q11, Q12, Q21, Q22);
  CSWAP(w0, w1, Q00, Q01, Q10, Q11, Q20, Q21);
#undef CSWAP

  Q[0][0] = Q00; Q[0][1] = Q01; Q[0][2] = Q02;
  Q[1][0] = Q10; Q[1][1] = Q11; Q[1][2] = Q12;
  Q[2][0] = Q20; Q[2][1] = Q21; Q[2][2] = Q22;
}

// ---------------------------------------------------------------------------
// Single fused kernel: bounds (cooperative 8-ary search) + LDS-staged moments
// + eigen + sign + output. 16 lanes/graph, 16 graphs per 256-thread block.
// ---------------------------------------------------------------------------
__global__ __launch_bounds__(256) void canon_all_kernel(
    const float* __restrict__ pos, const int* __restrict__ batch,
    float* __restrict__ out, int n, int G) {
  __shared__ float spos[MAX_STAGE * 3 + 8];  // staged dwords (x,y,z stream)
  __shared__ float lmom[16][9];   // cx,cy,cz,ixx,iyy,izz,ixy,ixz,iyz
  __shared__ float latm[16][12];  // first 4 atoms (fallback path only)
  __shared__ int lsc[16][2];      // s, cnt per local graph

  int tid = (int)threadIdx.x;
  int lg = tid >> 4;    // local graph index within block
  int sub = tid & 15;   // lane within subgroup
  int lane = tid & 63;  // lane within wave
  int gid = (int)blockIdx.x * 16 + lg;
  bool gv = gid < G;

  // ---- cooperative 8-ary lower-bound search ------------------------------
  int t0 = gv ? gid : (G - 1);
  int half = (lane >> 3) & 1;  // 0: target t0, 1: target t0+1
  int tgt = t0 + half;
  int j = lane & 7;            // probe slot (j=0: trivial true)
  int base = lane & 0x30;      // subgroup's bit base in the 64-bit ballot

  int r = 1;
  while (r < n) r <<= 3;       // power of 8 >= n (wave-uniform)
  int lo0 = 0, lo1 = 0;
  while (r > 1) {
    int step = r >> 3;
    int myLo = half ? lo1 : lo0;
    int m = myLo + j * step;   // probe: lb >= m  <=>  batch[m-1] < tgt
    int mm = m - 1;
    mm = mm < 0 ? 0 : (mm > n - 1 ? n - 1 : mm);
    bool c = (j == 0) || ((m <= n) && (batch[mm] < tgt));
    unsigned long long b = __ballot(c);
    unsigned c0 = (unsigned)((b >> base) & 0xFEull);        // bits 1..7
    unsigned c1 = (unsigned)((b >> (base + 8)) & 0xFEull);  // bits 1..7
    lo0 += __popc(c0) * step;
    lo1 += __popc(c1) * step;
    r = step;
  }
  {  // final fix-up: lb = lo + (batch[lo] < tgt)
    int i0 = lo0 < n - 1 ? lo0 : n - 1;
    int i1 = lo1 < n - 1 ? lo1 : n - 1;
    lo0 += ((lo0 < n) && (batch[i0] < t0)) ? 1 : 0;
    lo1 += ((lo1 < n) && (batch[i1] < t0 + 1)) ? 1 : 0;
  }
  int s = lo0, e = lo1;
  int cnt = e - s;

  if (sub == 0) { lsc[lg][0] = s; lsc[lg][1] = cnt; }
  __syncthreads();

  // ---- block atom range; cooperative float4 staging into LDS -------------
  int lastLg = G - 1 - (int)blockIdx.x * 16;
  lastLg = lastLg > 15 ? 15 : lastLg;
  int sB = lsc[0][0];
  int eB = lsc[lastLg][0] + lsc[lastLg][1];
  int range = eB - sB;
  bool useLds = (range <= MAX_STAGE);

  int d0 = (3 * sB) & ~3;       // 16B-aligned dword base
  if (useLds) {
    int numd = 3 * eB - d0;     // dwords to stage
    for (int d4 = tid * 4; d4 < numd; d4 += 256 * 4) {
      int gd = d0 + d4;
      if (gd + 4 <= 3 * n) {
        float4 v = *reinterpret_cast<const float4*>(pos + gd);
        spos[d4 + 0] = v.x; spos[d4 + 1] = v.y;
        spos[d4 + 2] = v.z; spos[d4 + 3] = v.w;
      } else {
        for (int q = 0; q < 4; ++q)
          if (gd + q < 3 * n) spos[d4 + q] = pos[gd + q];
      }
    }
  }
  __syncthreads();

  // ---- moments -----------------------------------------------------------
  float sx = 0.f, sy = 0.f, sz = 0.f;
  float sxx = 0.f, syy = 0.f, szz = 0.f, sxy = 0.f, sxz = 0.f, syz = 0.f;

  if (useLds) {
    for (int i = s + sub; i < e; i += 16) {
      int dd = 3 * i - d0;
      float x = spos[dd + 0];
      float y = spos[dd + 1];
      float z = spos[dd + 2];
      sx += x; sy += y; sz += z;
      sxx = fmaf(x, x, sxx); syy = fmaf(y, y, syy); szz = fmaf(z, z, szz);
      sxy = fmaf(x, y, sxy); sxz = fmaf(x, z, sxz); syz = fmaf(y, z, syz);
    }
  } else {
    // rare fallback: global clamped loads (R11 path)
    float r0x = 0.f, r0y = 0.f, r0z = 0.f;
#pragma unroll
    for (int k = 0; k < 5; ++k) {
      int i = s + sub + 16 * k;
      bool in = i < e;
      int ii = in ? i : 0;
      float rx = pos[3 * ii + 0];
      float ry = pos[3 * ii + 1];
      float rz = pos[3 * ii + 2];
      if (k == 0) { r0x = rx; r0y = ry; r0z = rz; }
      float m = in ? 1.0f : 0.0f;
      float x = rx * m, y = ry * m, z = rz * m;
      sx += x; sy += y; sz += z;
      sxx = fmaf(x, x, sxx); syy = fmaf(y, y, syy); szz = fmaf(z, z, szz);
      sxy = fmaf(x, y, sxy); sxz = fmaf(x, z, sxz); syz = fmaf(y, z, syz);
    }
    for (int i = s + 80 + sub; i < e; i += 16) {
      float x = pos[3 * i + 0];
      float y = pos[3 * i + 1];
      float z = pos[3 * i + 2];
      sx += x; sy += y; sz += z;
      sxx = fmaf(x, x, sxx); syy = fmaf(y, y, syy); szz = fmaf(z, z, szz);
      sxy = fmaf(x, y, sxy); sxz = fmaf(x, z, sxz); syz = fmaf(y, z, syz);
    }
    if (sub < 4 && gv) {
      latm[lg][3 * sub + 0] = r0x;
      latm[lg][3 * sub + 1] = r0y;
      latm[lg][3 * sub + 2] = r0z;
    }
  }

#define RED16(v)                                                             \
  v += __shfl_xor(v, 1); v += __shfl_xor(v, 2);                              \
  v += __shfl_xor(v, 4); v += __shfl_xor(v, 8);
  RED16(sx) RED16(sy) RED16(sz)
  RED16(sxx) RED16(syy) RED16(szz)
  RED16(sxy) RED16(sxz) RED16(syz)
#undef RED16

  if (sub == 0 && gv) {
    float fn = (float)(cnt > 0 ? cnt : 1);
    float inv = 1.0f / fn;
    float mx = sx * inv, my = sy * inv, mz = sz * inv;
    float Sxx = fmaf(-fn * mx, mx, sxx);
    float Syy = fmaf(-fn * my, my, syy);
    float Szz = fmaf(-fn * mz, mz, szz);
    float Sxy = fmaf(-fn * mx, my, sxy);
    float Sxz = fmaf(-fn * mx, mz, sxz);
    float Syz = fmaf(-fn * my, mz, syz);
    lmom[lg][0] = mx; lmom[lg][1] = my; lmom[lg][2] = mz;
    lmom[lg][3] = Syy + Szz;   // ixx
    lmom[lg][4] = Sxx + Szz;   // iyy
    lmom[lg][5] = Sxx + Syy;   // izz
    lmom[lg][6] = -Sxy;        // ixy
    lmom[lg][7] = -Sxz;        // ixz
    lmom[lg][8] = -Syz;        // iyz
  }
  __syncthreads();

  // ---- phase B: one thread per graph -------------------------------------
  if (tid < 16) {
    int g = (int)blockIdx.x * 16 + tid;
    if (g < G) {
      float cx = lmom[tid][0], cy = lmom[tid][1], cz = lmom[tid][2];
      float Q[3][3];
      jacobi3_f32(lmom[tid][3], lmom[tid][4], lmom[tid][5], lmom[tid][6],
                  lmom[tid][7], lmom[tid][8], Q);

      float q00 = Q[0][0], q10 = Q[1][0], q20 = Q[2][0];
      float q01 = Q[0][1], q11 = Q[1][1], q21 = Q[2][1];

      int s2 = lsc[tid][0];
      int cnt2 = lsc[tid][1];

      bool found0 = false, found1 = false;
      float v0s = 0.f, v1s = 0.f;
      if (useLds) {
        for (int k = 0; k < cnt2 && !(found0 && found1); ++k) {
          int dd = 3 * (s2 + k) - d0;
          float x = spos[dd + 0] - cx;
          float y = spos[dd + 1] - cy;
          float z = spos[dd + 2] - cz;
          float p0 = x * q00 + y * q10 + z * q20;
          float p1 = x * q01 + y * q11 + z * q21;
          if (!found0 && fabsf(p0) > CANON_EPS) { v0s = p0; found0 = true; }
          if (!found1 && fabsf(p1) > CANON_EPS) { v1s = p1; found1 = true; }
        }
      } else {
#define CHECK(J)                                                             \
  if ((J) < cnt2) {                                                          \
    float x = latm[tid][3 * (J) + 0] - cx;                                   \
    float y = latm[tid][3 * (J) + 1] - cy;                                   \
    float z = latm[tid][3 * (J) + 2] - cz;                                   \
    float p0 = x * q00 + y * q10 + z * q20;                                  \
    float p1 = x * q01 + y * q11 + z * q21;                                  \
    if (!found0 && fabsf(p0) > CANON_EPS) { v0s = p0; found0 = true; }       \
    if (!found1 && fabsf(p1) > CANON_EPS) { v1s = p1; found1 = true; }       \
  }
        CHECK(0) CHECK(1) CHECK(2) CHECK(3)
#undef CHECK
        for (int i = s2 + 4; i < s2 + cnt2 && !(found0 && found1); ++i) {
          float x = pos[3 * i + 0] - cx;
          float y = pos[3 * i + 1] - cy;
          float z = pos[3 * i + 2] - cz;
          float p0 = x * q00 + y * q10 + z * q20;
          float p1 = x * q01 + y * q11 + z * q21;
          if (!found0 && fabsf(p0) > CANON_EPS) { v0s = p0; found0 = true; }
          if (!found1 && fabsf(p1) > CANON_EPS) { v1s = p1; found1 = true; }
        }
      }
      float s0 = (found0 && v0s < 0.f) ? -1.f : 1.f;
      float s1 = (found1 && v1s < 0.f) ? -1.f : 1.f;

      float q0x = q00 * s0, q0y = q10 * s0, q0z = q20 * s0;
      float q1x = q01 * s1, q1y = q11 * s1, q1z = q21 * s1;
      float q2x = q0y * q1z - q0z * q1y;
      float q2y = q0z * q1x - q0x * q1z;
      float q2z = q0x * q1y - q0y * q1x;
      float* o = out + (size_t)g * 9;
      o[0] = q0x; o[1] = q1x; o[2] = q2x;
      o[3] = q0y; o[4] = q1y; o[5] = q2y;
      o[6] = q0z; o[7] = q1z; o[8] = q2z;
    }
  }
}

extern "C" void kernel_launch(void* const* d_in, const int* in_sizes, int n_in,
                              void* d_out, int out_size, void* d_ws, size_t ws_size,
                              hipStream_t stream) {
  const float* pos = (const float*)d_in[0];
  const int* batch = (const int*)d_in[1];
  float* out = (float*)d_out;

  int n = in_sizes[0] / 3;  // N atoms
  int G = out_size / 9;     // graphs

  canon_all_kernel<<<(G + 15) / 16, 256, 0, stream>>>(pos, batch, out, n, G);
}

// Round 13
// 22.365 us; speedup vs baseline: 1.0786x; 1.0786x over previous
//
#include <hip/hip_runtime.h>
#include <math.h>

#define CANON_EPS 1e-4f

// ---------------------------------------------------------------------------
// Branch-free 3x3 symmetric Jacobi eigensolver in f32, 4 cyclic sweeps.
// Columns of Q = eigenvectors; eigenvalues sorted ascending (matches eigh).
// ---------------------------------------------------------------------------
__device__ __forceinline__ void jacobi3_f32(float a00, float a11, float a22,
                                            float a01, float a02, float a12,
                                            float Q[3][3]) {
  float A00 = a00, A11 = a11, A22 = a22;
  float A01 = a01, A02 = a02, A12 = a12;
  float Q00 = 1.f, Q01 = 0.f, Q02 = 0.f;
  float Q10 = 0.f, Q11 = 1.f, Q12 = 0.f;
  float Q20 = 0.f, Q21 = 0.f, Q22 = 1.f;

#define ROT(App, Aqq, Apq, Akp, Akq, Qrp0, Qrq0, Qrp1, Qrq1, Qrp2, Qrq2)     \
  {                                                                          \
    float apq = Apq;                                                         \
    float theta = (Aqq - App) / (2.0f * apq);                                \
    float t = copysignf(1.0f, theta) /                                       \
              (fabsf(theta) + sqrtf(1.0f + theta * theta));                  \
    t = (apq == 0.0f) ? 0.0f : t; /* kills 0/0 NaN path */                   \
    float c = 1.0f / sqrtf(1.0f + t * t);                                    \
    float s = t * c;                                                         \
    App = App - t * apq;                                                     \
    Aqq = Aqq + t * apq;                                                     \
    Apq = 0.0f;                                                              \
    float akp = Akp, akq = Akq;                                              \
    Akp = c * akp - s * akq;                                                 \
    Akq = s * akp + c * akq;                                                 \
    float r0p = Qrp0, r0q = Qrq0;                                            \
    Qrp0 = c * r0p - s * r0q;                                                \
    Qrq0 = s * r0p + c * r0q;                                                \
    float r1p = Qrp1, r1q = Qrq1;                                            \
    Qrp1 = c * r1p - s * r1q;                                                \
    Qrq1 = s * r1p + c * r1q;                                                \
    float r2p = Qrp2, r2q = Qrq2;                                            \
    Qrp2 = c * r2p - s * r2q;                                                \
    Qrq2 = s * r2p + c * r2q;                                                \
  }

#pragma unroll
  for (int sweep = 0; sweep < 4; ++sweep) {
    ROT(A00, A11, A01, A02, A12, Q00, Q01, Q10, Q11, Q20, Q21);
    ROT(A00, A22, A02, A01, A12, Q00, Q02, Q10, Q12, Q20, Q22);
    ROT(A11, A22, A12, A01, A02, Q01, Q02, Q11, Q12, Q21, Q22);
  }
#undef ROT

  float w0 = A00, w1 = A11, w2 = A22;
#define CSWAP(wa, wb, qa0, qb0, qa1, qb1, qa2, qb2)                          \
  {                                                                          \
    bool sw = (wb) < (wa);                                                   \
    float tw = wa; wa = sw ? wb : wa; wb = sw ? tw : wb;                     \
    float t0 = qa0; qa0 = sw ? qb0 : qa0; qb0 = sw ? t0 : qb0;               \
    float t1 = qa1; qa1 = sw ? qb1 : qa1; qb1 = sw ? t1 : qb1;               \
    float t2 = qa2; qa2 = sw ? qb2 : qa2; qb2 = sw ? t2 : qb2;               \
  }
  CSWAP(w0, w1, Q00, Q01, Q10, Q11, Q20, Q21);
  CSWAP(w1, w2, Q01, Q02, Q11, Q12, Q21, Q22);
  CSWAP(w0, w1, Q00, Q01, Q10, Q11, Q20, Q21);
#undef CSWAP

  Q[0][0] = Q00; Q[0][1] = Q01; Q[0][2] = Q02;
  Q[1][0] = Q10; Q[1][1] = Q11; Q[1][2] = Q12;
  Q[2][0] = Q20; Q[2][1] = Q21; Q[2][2] = Q22;
}

// ---------------------------------------------------------------------------
// Single fused kernel: cooperative 8-ary bounds search + aligned-float4
// moments + eigen + sign + output. 16 lanes/graph, 16 graphs per 256-block.
// ---------------------------------------------------------------------------
__global__ __launch_bounds__(256) void canon_all_kernel(
    const float* __restrict__ pos, const int* __restrict__ batch,
    float* __restrict__ out, int n, int G) {
  __shared__ float lmom[16][9];   // cx,cy,cz,ixx,iyy,izz,ixy,ixz,iyz
  __shared__ float latm[16][24];  // atoms s4..s4+7, raw (lanes 0,1 round 0)
  __shared__ int lsc[16][3];      // s, cnt, o = s - s4

  int tid = (int)threadIdx.x;
  int lg = tid >> 4;    // local graph index within block
  int sub = tid & 15;   // lane within subgroup
  int lane = tid & 63;  // lane within wave
  int gid = (int)blockIdx.x * 16 + lg;
  bool gv = gid < G;

  // ---- cooperative 8-ary lower-bound search ------------------------------
  int t0 = gv ? gid : (G - 1);
  int half = (lane >> 3) & 1;  // 0: target t0, 1: target t0+1
  int tgt = t0 + half;
  int j = lane & 7;            // probe slot (j=0: trivial true)
  int base = lane & 0x30;      // subgroup's bit base in the 64-bit ballot

  int r = 1;
  while (r < n) r <<= 3;       // power of 8 >= n (wave-uniform)
  int lo0 = 0, lo1 = 0;
  while (r > 1) {
    int step = r >> 3;
    int myLo = half ? lo1 : lo0;
    int m = myLo + j * step;   // probe: lb >= m  <=>  batch[m-1] < tgt
    int mm = m - 1;
    mm = mm < 0 ? 0 : (mm > n - 1 ? n - 1 : mm);
    bool c = (j == 0) || ((m <= n) && (batch[mm] < tgt));
    unsigned long long b = __ballot(c);
    unsigned c0 = (unsigned)((b >> base) & 0xFEull);        // bits 1..7
    unsigned c1 = (unsigned)((b >> (base + 8)) & 0xFEull);  // bits 1..7
    lo0 += __popc(c0) * step;
    lo1 += __popc(c1) * step;
    r = step;
  }
  {  // final fix-up: lb = lo + (batch[lo] < tgt)
    int i0 = lo0 < n - 1 ? lo0 : n - 1;
    int i1 = lo1 < n - 1 ? lo1 : n - 1;
    lo0 += ((lo0 < n) && (batch[i0] < t0)) ? 1 : 0;
    lo1 += ((lo1 < n) && (batch[i1] < t0 + 1)) ? 1 : 0;
  }
  int s = lo0, e = lo1;
  int cnt = e - s;
  int s4 = s & ~3;  // 4-atom-aligned base => 16B-aligned float4 loads

  // ---- moments: 2 rounds x 4 atoms/lane via 3 aligned float4 loads -------
  float sx = 0.f, sy = 0.f, sz = 0.f;
  float sxx = 0.f, syy = 0.f, szz = 0.f, sxy = 0.f, sxz = 0.f, syz = 0.f;

#pragma unroll
  for (int rr = 0; rr < 2; ++rr) {
    int abase = s4 + 64 * rr + 4 * sub;  // multiple of 4
    bool okload = (abase + 4 <= n);      // whole 48B chunk in-bounds
    int dbase = okload ? 3 * abase : 0;  // dword index, multiple of 4
    const float4* p = reinterpret_cast<const float4*>(pos + dbase);
    float4 v0 = p[0];
    float4 v1 = p[1];
    float4 v2 = p[2];
    if (rr == 0 && sub < 2 && gv) {  // stash atoms s4..s4+7 raw for phase B
      float* d = &latm[lg][sub * 12];
      d[0] = v0.x; d[1] = v0.y; d[2]  = v0.z; d[3]  = v0.w;
      d[4] = v1.x; d[5] = v1.y; d[6]  = v1.z; d[7]  = v1.w;
      d[8] = v2.x; d[9] = v2.y; d[10] = v2.z; d[11] = v2.w;
    }
#define ACC(Q_, X, Y, Z)                                                     \
    {                                                                        \
      float m = ((unsigned)(abase + (Q_) - s) < (unsigned)cnt &&             \
                 okload) ? 1.0f : 0.0f;                                      \
      float x = (X) * m, y = (Y) * m, z = (Z) * m;                           \
      sx += x; sy += y; sz += z;                                             \
      sxx = fmaf(x, x, sxx); syy = fmaf(y, y, syy); szz = fmaf(z, z, szz);   \
      sxy = fmaf(x, y, sxy); sxz = fmaf(x, z, sxz); syz = fmaf(y, z, syz);   \
    }
    ACC(0, v0.x, v0.y, v0.z)
    ACC(1, v0.w, v1.x, v1.y)
    ACC(2, v1.z, v1.w, v2.x)
    ACC(3, v2.y, v2.z, v2.w)
#undef ACC
  }
  // rare epilogue: graphs extending past s4+128 (cnt >= 125)
  for (int i = s4 + 128 + sub; i < e; i += 16) {
    float x = pos[3 * i + 0];
    float y = pos[3 * i + 1];
    float z = pos[3 * i + 2];
    sx += x; sy += y; sz += z;
    sxx = fmaf(x, x, sxx); syy = fmaf(y, y, syy); szz = fmaf(z, z, szz);
    sxy = fmaf(x, y, sxy); sxz = fmaf(x, z, sxz); syz = fmaf(y, z, syz);
  }

#define RED16(v)                                                             \
  v += __shfl_xor(v, 1); v += __shfl_xor(v, 2);                              \
  v += __shfl_xor(v, 4); v += __shfl_xor(v, 8);
  RED16(sx) RED16(sy) RED16(sz)
  RED16(sxx) RED16(syy) RED16(szz)
  RED16(sxy) RED16(sxz) RED16(syz)
#undef RED16

  if (sub == 0 && gv) {
    float fn = (float)(cnt > 0 ? cnt : 1);
    float inv = 1.0f / fn;
    float mx = sx * inv, my = sy * inv, mz = sz * inv;
    float Sxx = fmaf(-fn * mx, mx, sxx);
    float Syy = fmaf(-fn * my, my, syy);
    float Szz = fmaf(-fn * mz, mz, szz);
    float Sxy = fmaf(-fn * mx, my, sxy);
    float Sxz = fmaf(-fn * mx, mz, sxz);
    float Syz = fmaf(-fn * my, mz, syz);
    lmom[lg][0] = mx; lmom[lg][1] = my; lmom[lg][2] = mz;
    lmom[lg][3] = Syy + Szz;   // ixx
    lmom[lg][4] = Sxx + Szz;   // iyy
    lmom[lg][5] = Sxx + Syy;   // izz
    lmom[lg][6] = -Sxy;        // ixy
    lmom[lg][7] = -Sxz;        // ixz
    lmom[lg][8] = -Syz;        // iyz
    lsc[lg][0] = s; lsc[lg][1] = cnt; lsc[lg][2] = s - s4;
  }
  __syncthreads();

  // ---- phase B: one thread per graph -------------------------------------
  if (tid < 16) {
    int g = (int)blockIdx.x * 16 + tid;
    if (g < G) {
      float cx = lmom[tid][0], cy = lmom[tid][1], cz = lmom[tid][2];
      float Q[3][3];
      jacobi3_f32(lmom[tid][3], lmom[tid][4], lmom[tid][5], lmom[tid][6],
                  lmom[tid][7], lmom[tid][8], Q);

      float q00 = Q[0][0], q10 = Q[1][0], q20 = Q[2][0];
      float q01 = Q[0][1], q11 = Q[1][1], q21 = Q[2][1];

      int s2 = lsc[tid][0];
      int cnt2 = lsc[tid][1];
      int o = lsc[tid][2];  // first atom of graph = latm slot o

      bool found0 = false, found1 = false;
      float v0s = 0.f, v1s = 0.f;
#define CHECK(J)                                                             \
  if ((J) < cnt2) {                                                          \
    float x = latm[tid][3 * (o + (J)) + 0] - cx;                             \
    float y = latm[tid][3 * (o + (J)) + 1] - cy;                             \
    float z = latm[tid][3 * (o + (J)) + 2] - cz;                             \
    float p0 = x * q00 + y * q10 + z * q20;                                  \
    float p1 = x * q01 + y * q11 + z * q21;                                  \
    if (!found0 && fabsf(p0) > CANON_EPS) { v0s = p0; found0 = true; }       \
    if (!found1 && fabsf(p1) > CANON_EPS) { v1s = p1; found1 = true; }       \
  }
      CHECK(0) CHECK(1) CHECK(2) CHECK(3)
#undef CHECK
      // ~never taken: sign not decided within the first 4 atoms
      for (int i = s2 + 4; i < s2 + cnt2 && !(found0 && found1); ++i) {
        float x = pos[3 * i + 0] - cx;
        float y = pos[3 * i + 1] - cy;
        float z = pos[3 * i + 2] - cz;
        float p0 = x * q00 + y * q10 + z * q20;
        float p1 = x * q01 + y * q11 + z * q21;
        if (!found0 && fabsf(p0) > CANON_EPS) { v0s = p0; found0 = true; }
        if (!found1 && fabsf(p1) > CANON_EPS) { v1s = p1; found1 = true; }
      }
      float s0 = (found0 && v0s < 0.f) ? -1.f : 1.f;
      float s1 = (found1 && v1s < 0.f) ? -1.f : 1.f;

      float q0x = q00 * s0, q0y = q10 * s0, q0z = q20 * s0;
      float q1x = q01 * s1, q1y = q11 * s1, q1z = q21 * s1;
      float q2x = q0y * q1z - q0z * q1y;
      float q2y = q0z * q1x - q0x * q1z;
      float q2z = q0x * q1y - q0y * q1x;
      float* o9 = out + (size_t)g * 9;
      o9[0] = q0x; o9[1] = q1x; o9[2] = q2x;
      o9[3] = q0y; o9[4] = q1y; o9[5] = q2y;
      o9[6] = q0z; o9[7] = q1z; o9[8] = q2z;
    }
  }
}

extern "C" void kernel_launch(void* const* d_in, const int* in_sizes, int n_in,
                              void* d_out, int out_size, void* d_ws, size_t ws_size,
                              hipStream_t stream) {
  const float* pos = (const float*)d_in[0];
  const int* batch = (const int*)d_in[1];
  float* out = (float*)d_out;

  int n = in_sizes[0] / 3;  // N atoms
  int G = out_size / 9;     // graphs

  canon_all_kernel<<<(G + 15) / 16, 256, 0, stream>>>(pos, batch, out, n, G);
}